// Round 1
// baseline (378.372 us; speedup 1.0000x reference)
//
#include <hip/hip_runtime.h>

// Problem constants
#define B_  16
#define T_  12
#define N_  1000
#define F_  64
#define KC  3
#define O_  64
#define NP  1024            // padded N (both i and j dims)
#define KP  (KC * NP)       // 3072 combined contraction length per b
#define CC  (T_ * O_)       // 768 output columns per b

typedef __bf16 bf16x8 __attribute__((ext_vector_type(8)));
typedef float  f32x4  __attribute__((ext_vector_type(4)));

__device__ __forceinline__ unsigned short f2bf(float f) {
  __bf16 h = (__bf16)f;                      // RNE convert
  return __builtin_bit_cast(unsigned short, h);
}

// async global->LDS, 16B per lane. LDS dest = wave-uniform base + lane*16.
__device__ __forceinline__ void gl_lds16(const void* g, void* l) {
  __builtin_amdgcn_global_load_lds(
      (const __attribute__((address_space(1))) unsigned int*)g,
      (__attribute__((address_space(3))) unsigned int*)l,
      16, 0, 0);
}

// ---------------------------------------------------------------------------
// Stage 1: ASt[b][ip][k][jp] = bf16(cheb[k,j,i] * SAtt[b,j,i]), zero-padded.
// 64x64 (j x i) tile, transpose via LDS. grid (i-tile, j-tile, b) = (16,16,16)
// ---------------------------------------------------------------------------
__global__ __launch_bounds__(256) void k_build_as(
    const float* __restrict__ SAtt, const float* __restrict__ cheb,
    unsigned short* __restrict__ ASt) {
  __shared__ unsigned short prod[KC][64][65];   // +1 pad breaks transpose conflicts
  const int tid = threadIdx.x;
  const int b = blockIdx.z, ib = blockIdx.x * 64, jb = blockIdx.y * 64;

  // load phase: coalesced in i (contiguous dim of SAtt/cheb)
  const int ii = tid & 63, j0 = tid >> 6;
  for (int p = 0; p < 16; ++p) {
    const int jj = p * 4 + j0;
    const int gi = ib + ii, gj = jb + jj;
    const bool ok = (gi < N_) && (gj < N_);
    const int gic = gi < N_ ? gi : N_ - 1;
    const int gjc = gj < N_ ? gj : N_ - 1;
    const float s = SAtt[(size_t)(b * N_ + gjc) * N_ + gic];
#pragma unroll
    for (int k = 0; k < KC; ++k) {
      const float c = cheb[(size_t)(k * N_ + gjc) * N_ + gic];
      prod[k][jj][ii] = ok ? f2bf(s * c) : (unsigned short)0;
    }
  }
  __syncthreads();

  // write phase: coalesced in j (contiguous dim of ASt), ushort4 = 8B/lane
  const int jq = (tid & 15) * 4, i0 = tid >> 4;
  for (int p = 0; p < 4; ++p) {
    const int iw = p * 16 + i0;
#pragma unroll
    for (int k = 0; k < KC; ++k) {
      ushort4 v;
      v.x = prod[k][jq + 0][iw];
      v.y = prod[k][jq + 1][iw];
      v.z = prod[k][jq + 2][iw];
      v.w = prod[k][jq + 3][iw];
      *(ushort4*)&ASt[((size_t)(b * NP + ib + iw) * KC + k) * NP + (jb + jq)] = v;
    }
  }
}

// ---------------------------------------------------------------------------
// Stage 2: Yt[b][t][o][k][jp] = bf16(sum_f x[b,t,j,f] * Theta[k,f,o]).
// MFMA with A = Theta^T (M=o=64), B = x (N=j=128), K=f=64.
// C-layout col = lane&15 -> j  => j-contiguous coalesced stores.
// grid (j-tile, b*T) = (8, 192), 256 threads.
// ---------------------------------------------------------------------------
__global__ __launch_bounds__(256) void k_build_y(
    const float* __restrict__ x, const float* __restrict__ Theta,
    unsigned short* __restrict__ Yt) {
  __shared__ unsigned short thl[KC][64][72];  // Theta^T [k][o][f], padded rows
  __shared__ unsigned short xl[128][72];      // x tile [j][f], padded rows
  const int tid = threadIdx.x;
  const int bt = blockIdx.y;                  // b*T + t
  const int jb = blockIdx.x * 128;

  // Theta -> thl (transposed), 12288 elems
  for (int idx = tid; idx < KC * F_ * O_; idx += 256) {
    const int k = idx >> 12, f = (idx >> 6) & 63, o = idx & 63;
    thl[k][o][f] = f2bf(Theta[idx]);
  }
  // x chunk (contiguous 128 rows x 64 f) -> xl as bf16
  const float* xrow = x + ((size_t)bt * N_ + jb) * F_;
  for (int p = 0; p < 8; ++p) {
    const int i4 = tid + p * 256;            // float4 index, 0..2047
    const int fl = i4 * 4, j = fl >> 6, f = fl & 63;
    float4 v;
    if (jb + j < N_) v = ((const float4*)xrow)[i4];
    else             v = make_float4(0.f, 0.f, 0.f, 0.f);
    ushort4 u;
    u.x = f2bf(v.x); u.y = f2bf(v.y); u.z = f2bf(v.z); u.w = f2bf(v.w);
    *(ushort4*)&xl[j][f] = u;
  }
  __syncthreads();

  const int w = tid >> 6, l = tid & 63, quad = l >> 4, lr = l & 15;
#pragma unroll
  for (int k = 0; k < KC; ++k) {
    f32x4 acc[4][2];
#pragma unroll
    for (int mi = 0; mi < 4; ++mi)
#pragma unroll
      for (int ni = 0; ni < 2; ++ni)
        acc[mi][ni] = (f32x4){0.f, 0.f, 0.f, 0.f};
#pragma unroll
    for (int ks = 0; ks < 2; ++ks) {
      const int fo = ks * 32 + quad * 8;
      bf16x8 a[4], bb[2];
#pragma unroll
      for (int mi = 0; mi < 4; ++mi)
        a[mi] = *(const bf16x8*)&thl[k][mi * 16 + lr][fo];
#pragma unroll
      for (int ni = 0; ni < 2; ++ni)
        bb[ni] = *(const bf16x8*)&xl[w * 32 + ni * 16 + lr][fo];
#pragma unroll
      for (int mi = 0; mi < 4; ++mi)
#pragma unroll
        for (int ni = 0; ni < 2; ++ni)
          acc[mi][ni] = __builtin_amdgcn_mfma_f32_16x16x32_bf16(
              a[mi], bb[ni], acc[mi][ni], 0, 0, 0);
    }
#pragma unroll
    for (int mi = 0; mi < 4; ++mi)
#pragma unroll
      for (int ni = 0; ni < 2; ++ni)
#pragma unroll
        for (int r = 0; r < 4; ++r) {
          const int o = mi * 16 + quad * 4 + r;
          const int j = jb + w * 32 + ni * 16 + lr;
          Yt[((size_t)(bt * O_ + o) * KC + k) * NP + j] = f2bf(acc[mi][ni][r]);
        }
  }
}

// ---------------------------------------------------------------------------
// Stage 3: per-b GEMM  C[i,c] = sum_{K'} ASt[b][i][K'] * Yt[b][c][K'],
// M=1024(i), N=768(c=t*64+o), K=3072. 128x128 block tile, 4 waves x (64x64),
// 16x16x32 bf16 MFMA, BK=64, global_load_lds width-16 staging. ReLU fused.
// grid (c-tile, i-tile, b) = (6, 8, 16) = 768 blocks (~3/CU).
// ---------------------------------------------------------------------------
__global__ __launch_bounds__(256, 2) void k_gemm(
    const unsigned short* __restrict__ ASt, const unsigned short* __restrict__ Yt,
    float* __restrict__ out) {
  __shared__ unsigned short Al[128 * 64];   // [i-row][kk], 16 KB
  __shared__ unsigned short Bl[128 * 64];   // [c-row][kk], 16 KB
  const int tid = threadIdx.x;
  const int b = blockIdx.z, ib = blockIdx.y * 128, cb = blockIdx.x * 128;
  const unsigned short* Abase = ASt + ((size_t)b * NP + ib) * KP;
  const unsigned short* Bbase = Yt + ((size_t)b * CC + cb) * KP;
  const int w = tid >> 6, l = tid & 63, quad = l >> 4, lr = l & 15;
  const int wr = w & 1, wc = w >> 1;
  const int lrow = l >> 3, lchunk = l & 7;   // staging: 8 rows x 8 x 16B chunks

  f32x4 acc[4][4];
#pragma unroll
  for (int mi = 0; mi < 4; ++mi)
#pragma unroll
    for (int ci = 0; ci < 4; ++ci)
      acc[mi][ci] = (f32x4){0.f, 0.f, 0.f, 0.f};

  for (int kt = 0; kt < KP / 64; ++kt) {
    __syncthreads();                        // protect LDS from prior readers
    const int k0 = kt * 64;
#pragma unroll
    for (int s = 0; s < 4; ++s) {
      const int row = w * 32 + s * 8;       // wave-uniform LDS base row
      gl_lds16(Abase + (size_t)(row + lrow) * KP + k0 + lchunk * 8, &Al[row * 64]);
      gl_lds16(Bbase + (size_t)(row + lrow) * KP + k0 + lchunk * 8, &Bl[row * 64]);
    }
    __syncthreads();                        // drains vmcnt(0) -> LDS valid
#pragma unroll
    for (int ks = 0; ks < 2; ++ks) {
      const int ko = ks * 32 + quad * 8;
      bf16x8 a[4], bb[4];
#pragma unroll
      for (int mi = 0; mi < 4; ++mi)
        a[mi] = *(const bf16x8*)&Al[(wr * 64 + mi * 16 + lr) * 64 + ko];
#pragma unroll
      for (int ci = 0; ci < 4; ++ci)
        bb[ci] = *(const bf16x8*)&Bl[(wc * 64 + ci * 16 + lr) * 64 + ko];
#pragma unroll
      for (int mi = 0; mi < 4; ++mi)
#pragma unroll
        for (int ci = 0; ci < 4; ++ci)
          acc[mi][ci] = __builtin_amdgcn_mfma_f32_16x16x32_bf16(
              a[mi], bb[ci], acc[mi][ci], 0, 0, 0);
    }
  }

  // epilogue: C/D layout col=lane&15 (->c), row=quad*4+reg (->i). ReLU fused.
#pragma unroll
  for (int mi = 0; mi < 4; ++mi) {
    const int i = ib + wr * 64 + mi * 16 + quad * 4;
#pragma unroll
    for (int ci = 0; ci < 4; ++ci) {
      const int c = cb + wc * 64 + ci * 16 + lr;
      const int t = c >> 6, o = c & 63;      // 16-aligned tile: single t
#pragma unroll
      for (int r = 0; r < 4; ++r) {
        if (i + r < N_) {
          const float v = acc[mi][ci][r];
          out[((size_t)(b * T_ + t) * N_ + (i + r)) * O_ + o] = v > 0.f ? v : 0.f;
        }
      }
    }
  }
}

// ---------------------------------------------------------------------------
extern "C" void kernel_launch(void* const* d_in, const int* in_sizes, int n_in,
                              void* d_out, int out_size, void* d_ws, size_t ws_size,
                              hipStream_t stream) {
  const float* x     = (const float*)d_in[0];
  const float* SAtt  = (const float*)d_in[1];
  const float* cheb  = (const float*)d_in[2];
  const float* Theta = (const float*)d_in[3];
  float* out = (float*)d_out;

  unsigned short* ASt = (unsigned short*)d_ws;                 // 100.7 MB
  unsigned short* Yt  = ASt + (size_t)B_ * NP * KC * NP;       //  75.5 MB

  k_build_as<<<dim3(16, 16, B_), 256, 0, stream>>>(SAtt, cheb, ASt);
  k_build_y<<<dim3(8, B_ * T_), 256, 0, stream>>>(x, Theta, Yt);
  k_gemm<<<dim3(CC / 128, NP / 128, B_), 256, 0, stream>>>(ASt, Yt, out);
}

// Round 2
// 321.777 us; speedup vs baseline: 1.1759x; 1.1759x over previous
//
#include <hip/hip_runtime.h>

// Problem constants
#define B_  16
#define T_  12
#define N_  1000
#define F_  64
#define KC  3
#define O_  64
#define NP  1024            // padded N (both i and j dims)
#define KP  (KC * NP)       // 3072 combined contraction length per b
#define CC  (T_ * O_)       // 768 output columns per b

typedef __bf16 bf16x8 __attribute__((ext_vector_type(8)));
typedef float  f32x4  __attribute__((ext_vector_type(4)));

__device__ __forceinline__ unsigned short f2bf(float f) {
  __bf16 h = (__bf16)f;                      // RNE convert
  return __builtin_bit_cast(unsigned short, h);
}

// async global->LDS, 16B per lane. LDS dest = wave-uniform base + lane*16.
__device__ __forceinline__ void gl_lds16(const void* g, void* l) {
  __builtin_amdgcn_global_load_lds(
      (const __attribute__((address_space(1))) unsigned int*)g,
      (__attribute__((address_space(3))) unsigned int*)l,
      16, 0, 0);
}

// ---------------------------------------------------------------------------
// Stage 1: ASt[b][ip][k][jp] = bf16(cheb[k,j,i] * SAtt[b,j,i]), zero-padded.
// 64x64 (j x i) tile, transpose via LDS. float4 loads, uint4 stores.
// grid (i-tile, j-tile, b) = (16,16,16)
// ---------------------------------------------------------------------------
__global__ __launch_bounds__(256) void k_build_as(
    const float* __restrict__ SAtt, const float* __restrict__ cheb,
    unsigned short* __restrict__ ASt) {
  __shared__ unsigned short prod[KC][64][66];   // 66 -> 132B rows (4B aligned)
  const int tid = threadIdx.x;
  const int b = blockIdx.z, ib = blockIdx.x * 64, jb = blockIdx.y * 64;

  // load phase: float4 along i (contiguous dim), 16 j-rows per pass
  const int ii4 = (tid & 15) * 4, jr = tid >> 4;
#pragma unroll
  for (int p = 0; p < 4; ++p) {
    const int jj = p * 16 + jr;
    const int gj = jb + jj;
    const int gjc = gj < N_ ? gj : N_ - 1;
    const int gi = ib + ii4;                    // N_%4==0: f4 never straddles
    const bool iok = gi < N_;
    const bool ok = iok && (gj < N_);
    float4 s4 = make_float4(0.f, 0.f, 0.f, 0.f);
    if (iok) s4 = *(const float4*)&SAtt[((size_t)b * N_ + gjc) * N_ + gi];
#pragma unroll
    for (int k = 0; k < KC; ++k) {
      float4 c4 = make_float4(0.f, 0.f, 0.f, 0.f);
      if (iok) c4 = *(const float4*)&cheb[((size_t)k * N_ + gjc) * N_ + gi];
      ushort2 lo, hi;
      lo.x = ok ? f2bf(c4.x * s4.x) : (unsigned short)0;
      lo.y = ok ? f2bf(c4.y * s4.y) : (unsigned short)0;
      hi.x = ok ? f2bf(c4.z * s4.z) : (unsigned short)0;
      hi.y = ok ? f2bf(c4.w * s4.w) : (unsigned short)0;
      *(ushort2*)&prod[k][jj][ii4]     = lo;
      *(ushort2*)&prod[k][jj][ii4 + 2] = hi;
    }
  }
  __syncthreads();

  // write phase: uint4 (8 bf16, 16B) per lane along j; 32 i-rows per pass
  const int j8 = (tid & 7) * 8, i0 = tid >> 3;
#pragma unroll
  for (int p = 0; p < 2; ++p) {
    const int iw = p * 32 + i0;
#pragma unroll
    for (int k = 0; k < KC; ++k) {
      unsigned short v[8];
#pragma unroll
      for (int m = 0; m < 8; ++m) v[m] = prod[k][j8 + m][iw];
      *(uint4*)&ASt[((size_t)(b * NP + ib + iw) * KC + k) * NP + jb + j8] =
          *(uint4*)v;
    }
  }
}

// ---------------------------------------------------------------------------
// Stage 2: Yt[b][t][o][k][jp] = bf16(sum_f x[b,t,j,f] * Theta[k,f,o]).
// MFMA A = Theta^T (M=o=64), B = x (N=j=128), K=f=64. Epilogue via LDS tile
// so global stores are uint4 (16B) coalesced. grid (j-tile, b*T) = (8, 192).
// ---------------------------------------------------------------------------
__global__ __launch_bounds__(256) void k_build_y(
    const float* __restrict__ x, const float* __restrict__ Theta,
    unsigned short* __restrict__ Yt) {
  __shared__ unsigned short thl[KC][64][72];  // Theta^T [k][o][f]
  __shared__ unsigned short xl[128][72];      // x tile [j][f]
  __shared__ unsigned short ot[64][136];      // out tile [o][j], 16B-aligned rows
  const int tid = threadIdx.x;
  const int bt = blockIdx.y;                  // b*T + t
  const int jb = blockIdx.x * 128;

  // Theta -> thl (transposed): float4 loads along o, scalar LDS writes
#pragma unroll
  for (int it = 0; it < 12; ++it) {
    const int e = (tid + it * 256) * 4;       // element index, mult of 4
    const int k = e >> 12, f = (e >> 6) & 63, o0 = e & 63;
    const float4 v = *(const float4*)&Theta[e];
    thl[k][o0 + 0][f] = f2bf(v.x);
    thl[k][o0 + 1][f] = f2bf(v.y);
    thl[k][o0 + 2][f] = f2bf(v.z);
    thl[k][o0 + 3][f] = f2bf(v.w);
  }
  // x chunk (128 j-rows x 64 f) -> xl as bf16, float4 loads
  const float* xrow = x + ((size_t)bt * N_ + jb) * F_;
#pragma unroll
  for (int p = 0; p < 8; ++p) {
    const int i4 = tid + p * 256;            // float4 index, 0..2047
    const int fl = i4 * 4, j = fl >> 6, f = fl & 63;
    float4 v;
    if (jb + j < N_) v = ((const float4*)xrow)[i4];
    else             v = make_float4(0.f, 0.f, 0.f, 0.f);
    ushort4 u;
    u.x = f2bf(v.x); u.y = f2bf(v.y); u.z = f2bf(v.z); u.w = f2bf(v.w);
    *(ushort4*)&xl[j][f] = u;
  }
  __syncthreads();

  const int w = tid >> 6, l = tid & 63, quad = l >> 4, lr = l & 15;
  const int o16 = tid >> 4, j8v = (tid & 15) * 8;
#pragma unroll
  for (int k = 0; k < KC; ++k) {
    f32x4 acc[4][2];
#pragma unroll
    for (int mi = 0; mi < 4; ++mi)
#pragma unroll
      for (int ni = 0; ni < 2; ++ni)
        acc[mi][ni] = (f32x4){0.f, 0.f, 0.f, 0.f};
#pragma unroll
    for (int ks = 0; ks < 2; ++ks) {
      const int fo = ks * 32 + quad * 8;
      bf16x8 a[4], bb[2];
#pragma unroll
      for (int mi = 0; mi < 4; ++mi)
        a[mi] = *(const bf16x8*)&thl[k][mi * 16 + lr][fo];
#pragma unroll
      for (int ni = 0; ni < 2; ++ni)
        bb[ni] = *(const bf16x8*)&xl[w * 32 + ni * 16 + lr][fo];
#pragma unroll
      for (int mi = 0; mi < 4; ++mi)
#pragma unroll
        for (int ni = 0; ni < 2; ++ni)
          acc[mi][ni] = __builtin_amdgcn_mfma_f32_16x16x32_bf16(
              a[mi], bb[ni], acc[mi][ni], 0, 0, 0);
    }
    __syncthreads();                          // protect ot from prior readers
#pragma unroll
    for (int mi = 0; mi < 4; ++mi)
#pragma unroll
      for (int ni = 0; ni < 2; ++ni)
#pragma unroll
        for (int r = 0; r < 4; ++r)
          ot[mi * 16 + quad * 4 + r][w * 32 + ni * 16 + lr] =
              f2bf(acc[mi][ni][r]);
    __syncthreads();
    // coalesced stores: 16 lanes x 16B = 256B contiguous per o-row
#pragma unroll
    for (int oo = 0; oo < 4; ++oo) {
      const int o = oo * 16 + o16;
      const uint4 v = *(const uint4*)&ot[o][j8v];
      *(uint4*)&Yt[((size_t)(bt * O_ + o) * KC + k) * NP + jb + j8v] = v;
    }
  }
}

// ---------------------------------------------------------------------------
// Stage 3: per-b GEMM  C[i,c] = sum_{K'} ASt[b][i][K'] * Yt[b][c][K'],
// M=1024(i), N=768(c), K=3072. 128x128 tile, 4 waves x (64x64), 16x16x32 bf16
// MFMA, BK=64, global_load_lds width-16. XOR chunk swizzle kills the 16-way
// LDS bank conflict of the 128B row stride. XCD-aware block swizzle (2 b/XCD).
// ---------------------------------------------------------------------------
__global__ __launch_bounds__(256, 2) void k_gemm(
    const unsigned short* __restrict__ ASt, const unsigned short* __restrict__ Yt,
    float* __restrict__ out) {
  __shared__ unsigned short Al[128 * 64];   // [row][K-chunk swizzled], 16 KB
  __shared__ unsigned short Bl[128 * 64];
  const int tid = threadIdx.x;
  // block swizzle: bid%8 -> XCD (HW round-robin heuristic); 2 b's per XCD
  const int bid = blockIdx.x;
  const int xcd = bid & 7, s = bid >> 3;          // s = 0..95
  const int b = xcd * 2 + (s / 48);
  const int r48 = s % 48;
  const int ib = (r48 / 6) * 128, cb = (r48 % 6) * 128;

  const unsigned short* Abase = ASt + ((size_t)b * NP + ib) * KP;
  const unsigned short* Bbase = Yt + ((size_t)b * CC + cb) * KP;
  const int w = tid >> 6, l = tid & 63, quad = l >> 4, lr = l & 15;
  const int wr = w & 1, wc = w >> 1;
  const int lrow = l >> 3, lchunk = l & 7;
  const int src_chunk = lchunk ^ lrow;            // XOR swizzle (staging side)
  const int p0 = quad ^ (lr & 7);                 // phys chunk, ks=0 (read side)

  f32x4 acc[4][4];
#pragma unroll
  for (int mi = 0; mi < 4; ++mi)
#pragma unroll
    for (int ci = 0; ci < 4; ++ci)
      acc[mi][ci] = (f32x4){0.f, 0.f, 0.f, 0.f};

  for (int kt = 0; kt < KP / 64; ++kt) {
    __syncthreads();                        // protect LDS from prior readers
    const int k0 = kt * 64;
#pragma unroll
    for (int s4 = 0; s4 < 4; ++s4) {
      const int row = w * 32 + s4 * 8;      // wave-uniform LDS base row
      gl_lds16(Abase + (size_t)(row + lrow) * KP + k0 + src_chunk * 8,
               &Al[row * 64]);
      gl_lds16(Bbase + (size_t)(row + lrow) * KP + k0 + src_chunk * 8,
               &Bl[row * 64]);
    }
    __syncthreads();                        // drains vmcnt(0) -> LDS valid
#pragma unroll
    for (int ks = 0; ks < 2; ++ks) {
      const int pc = (p0 ^ (ks * 4)) * 8;   // swizzled chunk -> ushort offset
      bf16x8 a[4], bb[4];
#pragma unroll
      for (int mi = 0; mi < 4; ++mi)
        a[mi] = *(const bf16x8*)&Al[(wr * 64 + mi * 16 + lr) * 64 + pc];
#pragma unroll
      for (int ci = 0; ci < 4; ++ci)
        bb[ci] = *(const bf16x8*)&Bl[(wc * 64 + ci * 16 + lr) * 64 + pc];
#pragma unroll
      for (int mi = 0; mi < 4; ++mi)
#pragma unroll
        for (int ci = 0; ci < 4; ++ci)
          acc[mi][ci] = __builtin_amdgcn_mfma_f32_16x16x32_bf16(
              a[mi], bb[ci], acc[mi][ci], 0, 0, 0);
    }
  }

  // epilogue: C/D layout col=lane&15 (->c), row=quad*4+reg (->i). ReLU fused.
#pragma unroll
  for (int mi = 0; mi < 4; ++mi) {
    const int i = ib + wr * 64 + mi * 16 + quad * 4;
#pragma unroll
    for (int ci = 0; ci < 4; ++ci) {
      const int c = cb + wc * 64 + ci * 16 + lr;
      const int t = c >> 6, o = c & 63;      // 16-aligned tile: single t
#pragma unroll
      for (int r = 0; r < 4; ++r) {
        if (i + r < N_) {
          const float v = acc[mi][ci][r];
          out[((size_t)(b * T_ + t) * N_ + (i + r)) * O_ + o] = v > 0.f ? v : 0.f;
        }
      }
    }
  }
}

// ---------------------------------------------------------------------------
extern "C" void kernel_launch(void* const* d_in, const int* in_sizes, int n_in,
                              void* d_out, int out_size, void* d_ws, size_t ws_size,
                              hipStream_t stream) {
  const float* x     = (const float*)d_in[0];
  const float* SAtt  = (const float*)d_in[1];
  const float* cheb  = (const float*)d_in[2];
  const float* Theta = (const float*)d_in[3];
  float* out = (float*)d_out;

  unsigned short* ASt = (unsigned short*)d_ws;                 // 100.7 MB
  unsigned short* Yt  = ASt + (size_t)B_ * NP * KC * NP;       //  75.5 MB

  k_build_as<<<dim3(16, 16, B_), 256, 0, stream>>>(SAtt, cheb, ASt);
  k_build_y<<<dim3(8, B_ * T_), 256, 0, stream>>>(x, Theta, Yt);
  k_gemm<<<768, 256, 0, stream>>>(ASt, Yt, out);
}